// Round 1
// baseline (338.378 us; speedup 1.0000x reference)
//
#include <hip/hip_runtime.h>
#include <cstdint>

#define NB1 8192
#define NB2 8192
#define DDIM 128
#define COLSPLIT 8
#define COLS_PER_BLOCK (NB2 / COLSPLIT)   // 1024
#define NCHUNK (COLS_PER_BLOCK / 64)      // 16

// ---------------------------------------------------------------------------
// Kernel 0: per-row squared norms for desc1/desc2 + init packed argmin keys.
// One wave (64 lanes) per row; float2 loads (512B contiguous per wave).
// ---------------------------------------------------------------------------
__global__ __launch_bounds__(256) void sq_init_kernel(
    const float* __restrict__ d1, const float* __restrict__ d2,
    float* __restrict__ asq, float* __restrict__ bsq,
    unsigned long long* __restrict__ packed) {
  int gid  = blockIdx.x * blockDim.x + threadIdx.x;
  int wave = gid >> 6;
  int lane = gid & 63;
  const float* src;
  float* dst;
  int row;
  if (wave < NB1) { src = d1; dst = asq; row = wave; }
  else            { src = d2; dst = bsq; row = wave - NB1; }
  float2 v = *(const float2*)&src[row * DDIM + lane * 2];
  float s = v.x * v.x + v.y * v.y;
  #pragma unroll
  for (int off = 32; off > 0; off >>= 1) s += __shfl_xor(s, off, 64);
  if (lane == 0) dst[row] = s;
  if (gid < NB1) packed[gid] = 0xFFFFFFFFFFFFFFFFull;  // +inf key (ws is poisoned)
}

// ---------------------------------------------------------------------------
// Kernel 1: fused  (bsq[j] - 2*dot(a_i,b_j))  GEMM + running argmin.
// 64x64 tile per (block.x tile-row, block.y column-split); 16 chunks of 64 cols.
// 16x16 threads, 4x4 micro-tile, STRIDED row/col assignment (m = ty+16r,
// n = tx+16c) so b128 LDS reads are <=2-way (free). B is XOR-swizzled
// (slot = k4 ^ (n&15)) so no padding is needed: LDS = exactly 64 KB.
// Result per row folded into a packed u64 (dist_bits<<32 | idx) via atomicMin
// -> lexicographic (dist, idx) min == first-occurrence argmin semantics.
// ---------------------------------------------------------------------------
__global__ __launch_bounds__(256) void match_kernel(
    const float* __restrict__ A, const float* __restrict__ Bm,
    const float* __restrict__ asq, const float* __restrict__ bsq,
    unsigned long long* __restrict__ packed) {
  __shared__ float smem[2 * 64 * 128];   // As[64][128] | Bs[64][128] = 64 KB
  float* As = smem;
  float* Bs = smem + 64 * 128;

  const int t  = threadIdx.x;
  const int tx = t & 15;
  const int ty = t >> 4;
  const int row0 = blockIdx.x * 64;
  const int col0 = blockIdx.y * COLS_PER_BLOCK;

  // ---- Load A tile once: 64 rows x 128 floats (coalesced float4). ----
  {
    const int r0 = t >> 5, k4 = t & 31;
    #pragma unroll
    for (int i = 0; i < 8; ++i) {
      int rr = r0 + 8 * i;
      *(float4*)&As[rr * 128 + 4 * k4] =
          *(const float4*)&A[(row0 + rr) * DDIM + 4 * k4];
    }
  }

  float bestv[4] = {1e30f, 1e30f, 1e30f, 1e30f};
  int   bestj[4] = {0, 0, 0, 0};

  for (int ch = 0; ch < NCHUNK; ++ch) {
    const int cbase = col0 + ch * 64;
    __syncthreads();  // previous chunk's readers done before overwriting Bs
    // ---- Load B chunk (64 cols x 128 k), XOR-swizzled k4 slots. ----
    {
      const int r0 = t >> 5, k4 = t & 31;
      #pragma unroll
      for (int i = 0; i < 8; ++i) {
        int n = r0 + 8 * i;
        *(float4*)&Bs[n * 128 + 4 * (k4 ^ (n & 15))] =
            *(const float4*)&Bm[(cbase + n) * DDIM + 4 * k4];
      }
    }
    __syncthreads();

    float acc[4][4] = {};
    #pragma unroll 4
    for (int k4 = 0; k4 < 32; ++k4) {
      float4 a4[4], b4[4];
      #pragma unroll
      for (int r = 0; r < 4; ++r)
        a4[r] = *(float4*)&As[(ty + 16 * r) * 128 + 4 * k4];
      #pragma unroll
      for (int c = 0; c < 4; ++c)
        b4[c] = *(float4*)&Bs[(tx + 16 * c) * 128 + 4 * (k4 ^ tx)];
      #pragma unroll
      for (int r = 0; r < 4; ++r)
        #pragma unroll
        for (int c = 0; c < 4; ++c) {
          acc[r][c] = fmaf(a4[r].x, b4[c].x, acc[r][c]);
          acc[r][c] = fmaf(a4[r].y, b4[c].y, acc[r][c]);
          acc[r][c] = fmaf(a4[r].z, b4[c].z, acc[r][c]);
          acc[r][c] = fmaf(a4[r].w, b4[c].w, acc[r][c]);
        }
    }

    // ---- Fold chunk into running (val, idx); j ascending in c => strict <
    //      preserves first-occurrence semantics within this thread. ----
    #pragma unroll
    for (int c = 0; c < 4; ++c) {
      int j = cbase + tx + 16 * c;
      float bq = bsq[j];
      #pragma unroll
      for (int r = 0; r < 4; ++r) {
        float val = fmaf(-2.f, acc[r][c], bq);
        if (val < bestv[r]) { bestv[r] = val; bestj[r] = j; }
      }
    }
  }

  // ---- Block reduction over the 16 tx-threads sharing each row. ----
  __syncthreads();
  float* rv = smem;                   // [64][16]
  int*   rj = (int*)(smem + 64 * 16); // [64][16]
  #pragma unroll
  for (int r = 0; r < 4; ++r) {
    int m = ty + 16 * r;
    rv[m * 16 + tx] = bestv[r];
    rj[m * 16 + tx] = bestj[r];
  }
  __syncthreads();
  if (t < 64) {
    int m = t;
    float bv = rv[m * 16];
    int   bj = rj[m * 16];
    #pragma unroll
    for (int x = 1; x < 16; ++x) {
      float v = rv[m * 16 + x];
      int   j = rj[m * 16 + x];
      if (v < bv || (v == bv && j < bj)) { bv = v; bj = j; }
    }
    float dm   = bv + asq[row0 + m];
    float dist = sqrtf(fmaxf(dm, 0.f));
    unsigned long long key =
        ((unsigned long long)__float_as_uint(dist) << 32) | (unsigned int)bj;
    atomicMin(&packed[row0 + m], key);
  }
}

// ---------------------------------------------------------------------------
// Kernel 2: unpack -> out[0:8192]=dists, out[8192+2i]=i, out[8192+2i+1]=idx.
// ---------------------------------------------------------------------------
__global__ __launch_bounds__(256) void out_kernel(
    const unsigned long long* __restrict__ packed, float* __restrict__ out) {
  int i = blockIdx.x * blockDim.x + threadIdx.x;
  if (i < NB1) {
    unsigned long long k = packed[i];
    out[i]               = __uint_as_float((unsigned int)(k >> 32));
    out[NB1 + 2 * i]     = (float)i;
    out[NB1 + 2 * i + 1] = (float)(unsigned int)(k & 0xFFFFFFFFull);
  }
}

extern "C" void kernel_launch(void* const* d_in, const int* in_sizes, int n_in,
                              void* d_out, int out_size, void* d_ws, size_t ws_size,
                              hipStream_t stream) {
  const float* d1 = (const float*)d_in[0];
  const float* d2 = (const float*)d_in[1];
  float* out = (float*)d_out;

  float* asq = (float*)d_ws;
  float* bsq = asq + NB1;
  unsigned long long* packed =
      (unsigned long long*)((char*)d_ws + (size_t)2 * NB1 * sizeof(float));

  // Kernel 0: norms + key init (re-done every call; ws is re-poisoned).
  sq_init_kernel<<<(NB1 + NB2) * 64 / 256, 256, 0, stream>>>(d1, d2, asq, bsq, packed);

  // Kernel 1: fused distance GEMM + argmin.
  dim3 grid(NB1 / 64, COLSPLIT);
  match_kernel<<<grid, 256, 0, stream>>>(d1, d2, asq, bsq, packed);

  // Kernel 2: write outputs.
  out_kernel<<<NB1 / 256, 256, 0, stream>>>(packed, out);
}

// Round 2
// 169.525 us; speedup vs baseline: 1.9960x; 1.9960x over previous
//
#include <hip/hip_runtime.h>
#include <cstdint>

#define NB1 8192
#define NB2 8192
#define DDIM 128
#define KTOT 384           // [hi | lo | hi] for A, [hi | hi | lo] for B
#define NKITER 12          // KTOT / 32
#define NCOLB 64           // 8192 / 128 column blocks

using half8  = __attribute__((ext_vector_type(8))) _Float16;
using half2v = __attribute__((ext_vector_type(2))) _Float16;
using float4v = __attribute__((ext_vector_type(4))) float;

typedef __attribute__((address_space(3))) void       lds_void;
typedef const __attribute__((address_space(1))) void glb_void;

__device__ inline unsigned long long packkey(float v, int j) {
  unsigned u = __float_as_uint(v);
  u = (u & 0x80000000u) ? ~u : (u | 0x80000000u);  // monotone float->uint
  return ((unsigned long long)u << 32) | (unsigned)j;
}

// ---------------------------------------------------------------------------
// Kernel 0: fp32 -> f16 hi/lo split (K=384 concat layout) + row squared norms.
// One wave per row.  A row: [ah(128) | al(128) | ah(128)]
//                    B row: [bh(128) | bh(128) | bl(128)]
// ---------------------------------------------------------------------------
__global__ __launch_bounds__(256) void convert_kernel(
    const float* __restrict__ d1, const float* __restrict__ d2,
    _Float16* __restrict__ A2, _Float16* __restrict__ B2,
    float* __restrict__ asq, float* __restrict__ bsq) {
  int gid  = blockIdx.x * 256 + threadIdx.x;
  int wrow = gid >> 6;
  int lane = gid & 63;
  bool isA = wrow < NB1;
  const float* src = isA ? d1 : d2;
  int row = isA ? wrow : wrow - NB1;

  float2 v = *(const float2*)&src[row * DDIM + lane * 2];
  _Float16 h0 = (_Float16)v.x, h1 = (_Float16)v.y;
  _Float16 l0 = (_Float16)(v.x - (float)h0);
  _Float16 l1 = (_Float16)(v.y - (float)h1);
  half2v hh = {h0, h1}, ll = {l0, l1};

  _Float16* dst = (isA ? A2 : B2) + (size_t)row * KTOT;
  int k2 = lane * 2;
  if (isA) {
    *(half2v*)&dst[k2]       = hh;
    *(half2v*)&dst[128 + k2] = ll;
    *(half2v*)&dst[256 + k2] = hh;
  } else {
    *(half2v*)&dst[k2]       = hh;
    *(half2v*)&dst[128 + k2] = hh;
    *(half2v*)&dst[256 + k2] = ll;
  }

  float s = v.x * v.x + v.y * v.y;
  #pragma unroll
  for (int off = 32; off > 0; off >>= 1) s += __shfl_xor(s, off, 64);
  if (lane == 0) (isA ? asq : bsq)[row] = s;
}

// ---------------------------------------------------------------------------
// Kernel 1: MFMA GEMM (A2 @ B2^T, K=384 f16, fp32 acc) + fused row argmin.
// 128x128 tile, 4 waves (2x2), each wave 4x4 tiles of mfma_f32_16x16x32_f16.
// global_load_lds width=16 staging, single-buffered 16 KB LDS.
// Epilogue: val = bsq[j] - 2*dot; per-lane c-reduce -> 4-step shuffle lex-min
// over the 16 lanes sharing a row -> LDS cross-wave combine -> one u64 key
// per row per block written to cand[colblock][row] (no atomics).
// ---------------------------------------------------------------------------
__global__ __launch_bounds__(256) void mfma_match_kernel(
    const _Float16* __restrict__ A2, const _Float16* __restrict__ B2,
    const float* __restrict__ bsq, unsigned long long* __restrict__ cand) {
  __shared__ _Float16 As[128 * 32];   // 8 KB
  __shared__ _Float16 Bs[128 * 32];   // 8 KB

  const int t    = threadIdx.x;
  const int lane = t & 63;
  const int wid  = t >> 6;
  const int wm = wid >> 1, wn = wid & 1;
  const int lx = lane & 15, q = lane >> 4;
  const int row0 = blockIdx.x * 128;
  const int col0 = blockIdx.y * 128;

  float4v acc[4][4];
  #pragma unroll
  for (int r = 0; r < 4; ++r)
    #pragma unroll
    for (int c = 0; c < 4; ++c) acc[r][c] = (float4v){0.f, 0.f, 0.f, 0.f};

  // Staging geometry: slab = 1 KB = 16 rows x 32 f16; wave wid stages slabs
  // {2*wid, 2*wid+1}. Lane l covers row slab*16 + l/4, k-offset (l&3)*8.
  const int sA   = wid * 2;
  const int rA0  = sA * 16 + (lane >> 2);
  const int kofs = (lane & 3) * 8;

  for (int kt = 0; kt < NKITER; ++kt) {
    const int k0 = kt * 32;
    __syncthreads();   // prior iter's LDS readers done
    {
      const _Float16* ga = A2 + (size_t)(row0 + rA0) * KTOT + k0 + kofs;
      __builtin_amdgcn_global_load_lds((glb_void*)ga,
          (lds_void*)(As + sA * 512), 16, 0, 0);
      __builtin_amdgcn_global_load_lds((glb_void*)(ga + 16 * KTOT),
          (lds_void*)(As + (sA + 1) * 512), 16, 0, 0);
      const _Float16* gb = B2 + (size_t)(col0 + rA0) * KTOT + k0 + kofs;
      __builtin_amdgcn_global_load_lds((glb_void*)gb,
          (lds_void*)(Bs + sA * 512), 16, 0, 0);
      __builtin_amdgcn_global_load_lds((glb_void*)(gb + 16 * KTOT),
          (lds_void*)(Bs + (sA + 1) * 512), 16, 0, 0);
    }
    __syncthreads();   // staging drained (compiler emits vmcnt(0) here)

    half8 af[4], bf[4];
    #pragma unroll
    for (int r = 0; r < 4; ++r)
      af[r] = *(const half8*)&As[(wm * 64 + 16 * r + lx) * 32 + q * 8];
    #pragma unroll
    for (int c = 0; c < 4; ++c)
      bf[c] = *(const half8*)&Bs[(wn * 64 + 16 * c + lx) * 32 + q * 8];
    #pragma unroll
    for (int r = 0; r < 4; ++r)
      #pragma unroll
      for (int c = 0; c < 4; ++c)
        acc[r][c] = __builtin_amdgcn_mfma_f32_16x16x32_f16(
            af[r], bf[c], acc[r][c], 0, 0, 0);
  }

  // ---- Epilogue: fused argmin. C/D layout: col = lane&15, row = q*4+reg. --
  int jc[4]; float bq[4];
  #pragma unroll
  for (int c = 0; c < 4; ++c) {
    jc[c] = col0 + wn * 64 + 16 * c + lx;
    bq[c] = bsq[jc[c]];
  }

  __syncthreads();                                   // done with As/Bs
  unsigned long long* red = (unsigned long long*)As; // [2][128] = 2 KB

  #pragma unroll
  for (int r = 0; r < 4; ++r) {
    #pragma unroll
    for (int reg = 0; reg < 4; ++reg) {
      float bv = 1e30f; int bj = 0;
      #pragma unroll
      for (int c = 0; c < 4; ++c) {   // jc ascending in c -> strict < keeps min j
        float val = fmaf(-2.f, acc[r][c][reg], bq[c]);
        if (val < bv) { bv = val; bj = jc[c]; }
      }
      #pragma unroll
      for (int m = 1; m <= 8; m <<= 1) {  // reduce over the 16 lanes sharing q
        float ov = __shfl_xor(bv, m, 64);
        int   oj = __shfl_xor(bj, m, 64);
        if (ov < bv || (ov == bv && oj < bj)) { bv = ov; bj = oj; }
      }
      if (lx == 0) {
        int mrow = wm * 64 + 16 * r + 4 * q + reg;
        red[wn * 128 + mrow] = packkey(bv, bj);
      }
    }
  }
  __syncthreads();
  if (t < 128) {
    unsigned long long k0v = red[t], k1v = red[128 + t];
    unsigned long long k = k0v < k1v ? k0v : k1v;
    cand[(size_t)blockIdx.y * NB1 + row0 + t] = k;
  }
}

// ---------------------------------------------------------------------------
// Kernel 2: reduce 64 column-block candidates per row, write outputs.
// u64 compare == lexicographic (val, idx) min == first-occurrence argmin.
// ---------------------------------------------------------------------------
__global__ __launch_bounds__(256) void final_kernel(
    const unsigned long long* __restrict__ cand,
    const float* __restrict__ asq, float* __restrict__ out) {
  int r = blockIdx.x * 256 + threadIdx.x;
  unsigned long long best = cand[r];
  #pragma unroll 8
  for (int cb = 1; cb < NCOLB; ++cb) {
    unsigned long long k = cand[(size_t)cb * NB1 + r];
    if (k < best) best = k;
  }
  unsigned u = (unsigned)(best >> 32);
  u = (u & 0x80000000u) ? (u & 0x7fffffffu) : ~u;   // invert monotone map
  float val  = __uint_as_float(u);
  float dm   = asq[r] + val;
  float dist = sqrtf(fmaxf(dm, 0.f));
  int j = (int)(unsigned)(best & 0xffffffffu);
  out[r]               = dist;
  out[NB1 + 2 * r]     = (float)r;
  out[NB1 + 2 * r + 1] = (float)j;
}

extern "C" void kernel_launch(void* const* d_in, const int* in_sizes, int n_in,
                              void* d_out, int out_size, void* d_ws, size_t ws_size,
                              hipStream_t stream) {
  const float* d1 = (const float*)d_in[0];
  const float* d2 = (const float*)d_in[1];
  float* out = (float*)d_out;

  char* w = (char*)d_ws;
  float* asq = (float*)w;                                   // 32 KB
  float* bsq = (float*)(w + 32768);                         // 32 KB
  _Float16* A2 = (_Float16*)(w + 65536);                    // 6 MB
  _Float16* B2 = (_Float16*)(w + 65536 + 6291456);          // 6 MB
  unsigned long long* cand =
      (unsigned long long*)(w + 65536 + 2 * 6291456);       // 4 MB

  // Kernel 0: split + norms. (8192+8192) rows, one wave per row.
  convert_kernel<<<(NB1 + NB2) / 4, 256, 0, stream>>>(d1, d2, A2, B2, asq, bsq);

  // Kernel 1: MFMA GEMM + fused argmin.
  dim3 grid(NB1 / 128, NB2 / 128);
  mfma_match_kernel<<<grid, 256, 0, stream>>>(A2, B2, bsq, cand);

  // Kernel 2: final reduce + output.
  final_kernel<<<NB1 / 256, 256, 0, stream>>>(cand, asq, out);
}

// Round 3
// 158.633 us; speedup vs baseline: 2.1331x; 1.0687x over previous
//
#include <hip/hip_runtime.h>
#include <cstdint>

#define NB1 8192
#define NB2 8192
#define DDIM 128
#define KTOT 384           // A row: [ah|al|ah], B row: [bh|bh|bl]
#define NKITER 12          // KTOT / 32
#define CTILES 4           // column tiles of 128 per block
#define GRIDY 16           // NB2 / (128*CTILES)

using half8   = __attribute__((ext_vector_type(8))) _Float16;
using half4   = __attribute__((ext_vector_type(4))) _Float16;
using float4v = __attribute__((ext_vector_type(4))) float;

typedef __attribute__((address_space(3))) void       lds_void;
typedef const __attribute__((address_space(1))) void glb_void;

__device__ inline unsigned long long packkey(float v, int j) {
  unsigned u = __float_as_uint(v);
  u = (u & 0x80000000u) ? ~u : (u | 0x80000000u);  // monotone float->uint
  return ((unsigned long long)u << 32) | (unsigned)j;
}

// ---------------------------------------------------------------------------
// Kernel 0: fp32 -> f16 hi/lo split (K=384 concat layout) + row squared norms.
// One wave per 2 rows; float4 loads (16 B/lane), half4 stores.
// ---------------------------------------------------------------------------
__global__ __launch_bounds__(256) void convert_kernel(
    const float* __restrict__ d1, const float* __restrict__ d2,
    _Float16* __restrict__ A2, _Float16* __restrict__ B2,
    float* __restrict__ asq, float* __restrict__ bsq) {
  int gid  = blockIdx.x * 256 + threadIdx.x;
  int wv   = gid >> 6;
  int lane = gid & 63;
  int rowc = 2 * wv + (lane >> 5);
  bool isA = rowc < NB1;
  const float* src = isA ? d1 : d2;
  int row = isA ? rowc : rowc - NB1;
  int k4  = (lane & 31) * 4;

  float4 v = *(const float4*)&src[row * DDIM + k4];
  _Float16 h0 = (_Float16)v.x, h1 = (_Float16)v.y;
  _Float16 h2 = (_Float16)v.z, h3 = (_Float16)v.w;
  half4 hh = {h0, h1, h2, h3};
  half4 ll = {(_Float16)(v.x - (float)h0), (_Float16)(v.y - (float)h1),
              (_Float16)(v.z - (float)h2), (_Float16)(v.w - (float)h3)};

  _Float16* dst = (isA ? A2 : B2) + (size_t)row * KTOT;
  *(half4*)&dst[k4]       = hh;
  *(half4*)&dst[128 + k4] = isA ? ll : hh;
  *(half4*)&dst[256 + k4] = isA ? hh : ll;

  float s = v.x * v.x + v.y * v.y + v.z * v.z + v.w * v.w;
  #pragma unroll
  for (int off = 16; off > 0; off >>= 1) s += __shfl_xor(s, off, 64);
  if ((lane & 31) == 0) (isA ? asq : bsq)[row] = s;
}

// ---------------------------------------------------------------------------
// Kernel 1: MFMA GEMM (A2 @ B2^T, K=384 f16, fp32 acc) + fused row argmin.
// 128x128 tile x 4 column tiles per block. 4 waves (2x2), each wave 4x4
// mfma_f32_16x16x32_f16. Double-buffered global_load_lds width-16 staging,
// stage(i+1) issued after the barrier so its latency hides behind compute(i).
// Per col-tile: fold acc into per-lane (val,idx) registers (no shuffles).
// Final: packed-u64 lex-min reduce through padded LDS -> 1 key/row/block.
// ---------------------------------------------------------------------------
__global__ __launch_bounds__(256, 3) void mfma_match_kernel(
    const _Float16* __restrict__ A2, const _Float16* __restrict__ B2,
    const float* __restrict__ bsq, unsigned long long* __restrict__ cand) {
  __shared__ unsigned long long smem[2 * 128 * 17];  // 34816 B (aliased below)
  _Float16* Asb = (_Float16*)smem;                   // 2 buffers x 4096 f16
  _Float16* Bsb = (_Float16*)smem + 8192;            // 2 buffers x 4096 f16

  const int t    = threadIdx.x;
  const int lane = t & 63;
  const int wid  = t >> 6;
  const int wm = wid >> 1, wn = wid & 1;
  const int lx = lane & 15, q = lane >> 4;
  const int row0    = blockIdx.x * 128;
  const int colbase = blockIdx.y * (128 * CTILES);

  // Staging geometry: slab = 1 KB = 16 rows x 32 f16; wave stages slabs
  // {2*wid, 2*wid+1}; lane l -> row slab*16 + l/4, k-chunk (l&3)*8.
  const int sA   = wid * 2;
  const int rA0  = sA * 16 + (lane >> 2);
  const int kofs = (lane & 3) * 8;

  float4v acc[4][4];
  #pragma unroll
  for (int r = 0; r < 4; ++r)
    #pragma unroll
    for (int c = 0; c < 4; ++c) acc[r][c] = (float4v){0.f, 0.f, 0.f, 0.f};

  float bestv[16];
  int   bestj[16];
  #pragma unroll
  for (int s = 0; s < 16; ++s) { bestv[s] = 1e30f; bestj[s] = 0; }

  auto stage = [&](int ct, int kt, int buf) {
    const _Float16* ga = A2 + (size_t)(row0 + rA0) * KTOT + kt * 32 + kofs;
    __builtin_amdgcn_global_load_lds((glb_void*)ga,
        (lds_void*)(Asb + buf * 4096 + sA * 512), 16, 0, 0);
    __builtin_amdgcn_global_load_lds((glb_void*)(ga + 16 * KTOT),
        (lds_void*)(Asb + buf * 4096 + (sA + 1) * 512), 16, 0, 0);
    const _Float16* gb =
        B2 + (size_t)(colbase + ct * 128 + rA0) * KTOT + kt * 32 + kofs;
    __builtin_amdgcn_global_load_lds((glb_void*)gb,
        (lds_void*)(Bsb + buf * 4096 + sA * 512), 16, 0, 0);
    __builtin_amdgcn_global_load_lds((glb_void*)(gb + 16 * KTOT),
        (lds_void*)(Bsb + buf * 4096 + (sA + 1) * 512), 16, 0, 0);
  };

  stage(0, 0, 0);

  for (int ct = 0; ct < CTILES; ++ct) {
    #pragma unroll
    for (int kt = 0; kt < NKITER; ++kt) {
      __syncthreads();  // compiler emits vmcnt(0): stage(i) drained; buffers safe
      // Prefetch next tile into the other buffer; overlaps with MFMA below.
      if (kt < NKITER - 1) {
        stage(ct, kt + 1, (kt + 1) & 1);
      } else if (ct < CTILES - 1) {
        stage(ct + 1, 0, 0);
      }
      const _Float16* Ab = Asb + (kt & 1) * 4096;
      const _Float16* Bb = Bsb + (kt & 1) * 4096;
      half8 af[4], bf[4];
      #pragma unroll
      for (int r = 0; r < 4; ++r)
        af[r] = *(const half8*)&Ab[(wm * 64 + 16 * r + lx) * 32 + q * 8];
      #pragma unroll
      for (int c = 0; c < 4; ++c)
        bf[c] = *(const half8*)&Bb[(wn * 64 + 16 * c + lx) * 32 + q * 8];
      #pragma unroll
      for (int r = 0; r < 4; ++r)
        #pragma unroll
        for (int c = 0; c < 4; ++c)
          acc[r][c] = __builtin_amdgcn_mfma_f32_16x16x32_f16(
              af[r], bf[c], acc[r][c], 0, 0, 0);
    }
    // ---- Fold this col-tile into per-lane running best (registers only).
    // j ascends with c and ct for fixed row+lane; strict < keeps first j.
    const int colt0 = colbase + ct * 128;
    #pragma unroll
    for (int c = 0; c < 4; ++c) {
      int j = colt0 + wn * 64 + 16 * c + lx;
      float bq = bsq[j];
      #pragma unroll
      for (int r = 0; r < 4; ++r)
        #pragma unroll
        for (int reg = 0; reg < 4; ++reg) {
          float val = fmaf(-2.f, acc[r][c][reg], bq);
          int s = r * 4 + reg;
          if (val < bestv[s]) { bestv[s] = val; bestj[s] = j; }
          acc[r][c][reg] = 0.f;
        }
    }
  }

  // ---- Cross-lane lex-min via padded LDS (C/D layout: row = q*4+reg). ----
  __syncthreads();  // all waves done reading staging LDS before aliasing
  #pragma unroll
  for (int s = 0; s < 16; ++s) {
    int r = s >> 2, reg = s & 3;
    int mrow = wm * 64 + 16 * r + 4 * q + reg;
    smem[(wn * 128 + mrow) * 17 + lx] = packkey(bestv[s], bestj[s]);
  }
  __syncthreads();
  if (t < 128) {
    unsigned long long best = ~0ull;
    #pragma unroll
    for (int w = 0; w < 2; ++w)
      #pragma unroll
      for (int x = 0; x < 16; ++x) {
        unsigned long long k = smem[(w * 128 + t) * 17 + x];
        if (k < best) best = k;
      }
    cand[(size_t)blockIdx.y * NB1 + row0 + t] = best;
  }
}

// ---------------------------------------------------------------------------
// Kernel 2: reduce GRIDY candidates per row, write outputs.
// ---------------------------------------------------------------------------
__global__ __launch_bounds__(256) void final_kernel(
    const unsigned long long* __restrict__ cand,
    const float* __restrict__ asq, float* __restrict__ out) {
  int r = blockIdx.x * 256 + threadIdx.x;
  unsigned long long best = cand[r];
  #pragma unroll
  for (int cb = 1; cb < GRIDY; ++cb) {
    unsigned long long k = cand[(size_t)cb * NB1 + r];
    if (k < best) best = k;
  }
  unsigned u = (unsigned)(best >> 32);
  u = (u & 0x80000000u) ? (u & 0x7fffffffu) : ~u;   // invert monotone map
  float val  = __uint_as_float(u);
  float dist = sqrtf(fmaxf(asq[r] + val, 0.f));
  int j = (int)(unsigned)(best & 0xffffffffu);
  out[r]               = dist;
  out[NB1 + 2 * r]     = (float)r;
  out[NB1 + 2 * r + 1] = (float)j;
}

extern "C" void kernel_launch(void* const* d_in, const int* in_sizes, int n_in,
                              void* d_out, int out_size, void* d_ws, size_t ws_size,
                              hipStream_t stream) {
  const float* d1 = (const float*)d_in[0];
  const float* d2 = (const float*)d_in[1];
  float* out = (float*)d_out;

  char* w = (char*)d_ws;
  float* asq = (float*)w;                                   // 32 KB
  float* bsq = (float*)(w + 32768);                         // 32 KB
  _Float16* A2 = (_Float16*)(w + 65536);                    // 6 MB
  _Float16* B2 = (_Float16*)(w + 65536 + 6291456);          // 6 MB
  unsigned long long* cand =
      (unsigned long long*)(w + 65536 + 2 * 6291456);       // 1 MB

  convert_kernel<<<(NB1 + NB2) / 8, 256, 0, stream>>>(d1, d2, A2, B2, asq, bsq);

  dim3 grid(NB1 / 128, GRIDY);
  mfma_match_kernel<<<grid, 256, 0, stream>>>(A2, B2, bsq, cand);

  final_kernel<<<NB1 / 256, 256, 0, stream>>>(cand, asq, out);
}

// Round 4
// 131.386 us; speedup vs baseline: 2.5755x; 1.2074x over previous
//
#include <hip/hip_runtime.h>
#include <cstdint>

#define NB1 8192
#define NB2 8192
#define DDIM 128
#define KROW 256           // stored row: [hi(128) | lo(128)] f16
#define NKITER 12          // virtual K = 384 (hi*hi + lo*hi + hi*lo)
#define NCOLB 64           // column tiles of 128

using half8   = __attribute__((ext_vector_type(8))) _Float16;
using half4   = __attribute__((ext_vector_type(4))) _Float16;
using float4v = __attribute__((ext_vector_type(4))) float;

typedef __attribute__((address_space(3))) void       lds_void;
typedef const __attribute__((address_space(1))) void glb_void;

__device__ inline unsigned long long packkey(float v, int j) {
  unsigned u = __float_as_uint(v);
  u = (u & 0x80000000u) ? ~u : (u | 0x80000000u);  // monotone float->uint
  return ((unsigned long long)u << 32) | (unsigned)j;
}

// virtual kt -> source 32-f16 chunk index within the [hi|lo] row
__device__ __forceinline__ int a_src(int kt) { return (kt < 8) ? kt : kt - 8; } // hi,lo,hi
__device__ __forceinline__ int b_src(int kt) { return (kt < 4) ? kt : kt - 4; } // hi,hi,lo

// ---------------------------------------------------------------------------
// Kernel 0: fp32 -> f16 hi/lo split (row = [hi|lo], 256 f16) + squared norms.
// One wave per 2 rows; float4 loads, half4 stores.
// ---------------------------------------------------------------------------
__global__ __launch_bounds__(256) void convert_kernel(
    const float* __restrict__ d1, const float* __restrict__ d2,
    _Float16* __restrict__ A2, _Float16* __restrict__ B2,
    float* __restrict__ asq, float* __restrict__ bsq) {
  int gid  = blockIdx.x * 256 + threadIdx.x;
  int wv   = gid >> 6;
  int lane = gid & 63;
  int rowc = 2 * wv + (lane >> 5);
  bool isA = rowc < NB1;
  const float* src = isA ? d1 : d2;
  int row = isA ? rowc : rowc - NB1;
  int k4  = (lane & 31) * 4;

  float4 v = *(const float4*)&src[row * DDIM + k4];
  _Float16 h0 = (_Float16)v.x, h1 = (_Float16)v.y;
  _Float16 h2 = (_Float16)v.z, h3 = (_Float16)v.w;
  half4 hh = {h0, h1, h2, h3};
  half4 ll = {(_Float16)(v.x - (float)h0), (_Float16)(v.y - (float)h1),
              (_Float16)(v.z - (float)h2), (_Float16)(v.w - (float)h3)};

  _Float16* dst = (isA ? A2 : B2) + (size_t)row * KROW;
  *(half4*)&dst[k4]       = hh;
  *(half4*)&dst[128 + k4] = ll;

  float s = v.x * v.x + v.y * v.y + v.z * v.z + v.w * v.w;
  #pragma unroll
  for (int off = 16; off > 0; off >>= 1) s += __shfl_xor(s, off, 64);
  if ((lane & 31) == 0) (isA ? asq : bsq)[row] = s;
}

// ---------------------------------------------------------------------------
// Kernel 1: MFMA GEMM (virtual K=384 f16, fp32 acc) + fused row argmin.
// 128x128 tile, 4 waves (2x2), 4x4 mfma_f32_16x16x32_f16 per wave.
// - XCD swizzle: per-XCD resident set = 8 A-tiles + 16 B-tiles (~2.4 MB < L2).
// - Double-buffered global_load_lds (16B) staging; one barrier per kt.
// - LDS cell (row r, chunk q) at 4r + ((q + (r>>1)) & 3): frag b128 reads hit
//   8 disjoint 4-bank windows, 2 lanes each -> conflict-free. Staging lanes
//   fetch the inverse-permuted global chunk (LDS side stays lane-contiguous).
// - Epilogue: register fold over c, pad-17 LDS lex-min -> 1 u64/row/block.
// ---------------------------------------------------------------------------
__global__ __launch_bounds__(256, 3) void mfma_match_kernel(
    const _Float16* __restrict__ A2, const _Float16* __restrict__ B2,
    const float* __restrict__ bsq, unsigned long long* __restrict__ cand) {
  __shared__ unsigned long long smem[2 * 128 * 17];  // 34816 B, aliased
  _Float16* Asb = (_Float16*)smem;                   // 2 buffers x 4096 f16
  _Float16* Bsb = (_Float16*)smem + 8192;            // 2 buffers x 4096 f16

  const int t    = threadIdx.x;
  const int lane = t & 63;
  const int wid  = t >> 6;
  const int wm = wid >> 1, wn = wid & 1;
  const int lx = lane & 15, q = lane >> 4;

  // L2/XCD locality swizzle (dispatch round-robins id%8 across XCDs).
  const int id = blockIdx.x;
  const int xc = id & 7, kk = id >> 3;
  const int bx = ((kk >> 3) & 7) * 8 + xc;
  const int by = (kk & 7) + ((kk >> 6) & 7) * 8;
  const int row0 = bx * 128, col0 = by * 128;

  // Staging lane geometry. Slab = 16 rows x 4 cells(16B). Wave stages slabs
  // {2*wid, 2*wid+1}. Lane l -> row l>>2, LDS slot l&3; the global chunk for
  // that slot is the inverse bank-swizzle: q = (slot - (row>>1)) & 3.
  const int sA   = wid * 2;
  const int rloc = lane >> 2;
  const int qch  = ((lane & 3) - (rloc >> 1)) & 3;
  const int rA0  = sA * 16 + rloc;
  const int kofs = qch * 8;

  float4v acc[4][4];
  #pragma unroll
  for (int r = 0; r < 4; ++r)
    #pragma unroll
    for (int c = 0; c < 4; ++c) acc[r][c] = (float4v){0.f, 0.f, 0.f, 0.f};

  // Prefetch bsq + column ids for the epilogue.
  float bq[4]; int jc[4];
  #pragma unroll
  for (int c = 0; c < 4; ++c) {
    jc[c] = col0 + wn * 64 + 16 * c + lx;
    bq[c] = bsq[jc[c]];
  }

  auto stage = [&](int kt, int buf) {
    const _Float16* ga =
        A2 + (size_t)(row0 + rA0) * KROW + a_src(kt) * 32 + kofs;
    __builtin_amdgcn_global_load_lds((glb_void*)ga,
        (lds_void*)(Asb + buf * 4096 + sA * 512), 16, 0, 0);
    __builtin_amdgcn_global_load_lds((glb_void*)(ga + 16 * KROW),
        (lds_void*)(Asb + buf * 4096 + (sA + 1) * 512), 16, 0, 0);
    const _Float16* gb =
        B2 + (size_t)(col0 + rA0) * KROW + b_src(kt) * 32 + kofs;
    __builtin_amdgcn_global_load_lds((glb_void*)gb,
        (lds_void*)(Bsb + buf * 4096 + sA * 512), 16, 0, 0);
    __builtin_amdgcn_global_load_lds((glb_void*)(gb + 16 * KROW),
        (lds_void*)(Bsb + buf * 4096 + (sA + 1) * 512), 16, 0, 0);
  };

  stage(0, 0);

  const int sw = ((q + (lx >> 1)) & 3) * 8;   // bank-swizzled chunk offset

  #pragma unroll
  for (int kt = 0; kt < NKITER; ++kt) {
    __syncthreads();  // stage(kt) drained (vmcnt0 before barrier); WAR safe
    if (kt < NKITER - 1) stage(kt + 1, (kt + 1) & 1);
    const _Float16* Ab = Asb + (kt & 1) * 4096;
    const _Float16* Bb = Bsb + (kt & 1) * 4096;
    half8 af[4], bf[4];
    #pragma unroll
    for (int r = 0; r < 4; ++r)
      af[r] = *(const half8*)&Ab[(wm * 64 + 16 * r + lx) * 32 + sw];
    #pragma unroll
    for (int c = 0; c < 4; ++c)
      bf[c] = *(const half8*)&Bb[(wn * 64 + 16 * c + lx) * 32 + sw];
    #pragma unroll
    for (int r = 0; r < 4; ++r)
      #pragma unroll
      for (int c = 0; c < 4; ++c)
        acc[r][c] = __builtin_amdgcn_mfma_f32_16x16x32_f16(
            af[r], bf[c], acc[r][c], 0, 0, 0);
  }

  // ---- Epilogue. C/D layout: col = lane&15, row = q*4 + reg. ----
  __syncthreads();  // all frag reads done before aliasing staging LDS
  #pragma unroll
  for (int r = 0; r < 4; ++r) {
    #pragma unroll
    for (int reg = 0; reg < 4; ++reg) {
      float bv = 1e30f; int bj = 0;
      #pragma unroll
      for (int c = 0; c < 4; ++c) {  // jc ascending -> strict < keeps min j
        float val = fmaf(-2.f, acc[r][c][reg], bq[c]);
        if (val < bv) { bv = val; bj = jc[c]; }
      }
      int mrow = wm * 64 + 16 * r + 4 * q + reg;
      smem[(wn * 128 + mrow) * 17 + lx] = packkey(bv, bj);
    }
  }
  __syncthreads();
  if (t < 128) {
    unsigned long long best = ~0ull;
    #pragma unroll
    for (int w = 0; w < 2; ++w)
      #pragma unroll
      for (int x = 0; x < 16; ++x) {
        unsigned long long k = smem[(w * 128 + t) * 17 + x];
        if (k < best) best = k;
      }
    cand[(size_t)by * NB1 + row0 + t] = best;
  }
}

// ---------------------------------------------------------------------------
// Kernel 2: reduce 64 column-block candidates per row, write outputs.
// ---------------------------------------------------------------------------
__global__ __launch_bounds__(256) void final_kernel(
    const unsigned long long* __restrict__ cand,
    const float* __restrict__ asq, float* __restrict__ out) {
  int r = blockIdx.x * 256 + threadIdx.x;
  unsigned long long best = cand[r];
  #pragma unroll 8
  for (int cb = 1; cb < NCOLB; ++cb) {
    unsigned long long k = cand[(size_t)cb * NB1 + r];
    if (k < best) best = k;
  }
  unsigned u = (unsigned)(best >> 32);
  u = (u & 0x80000000u) ? (u & 0x7fffffffu) : ~u;   // invert monotone map
  float val  = __uint_as_float(u);
  float dist = sqrtf(fmaxf(asq[r] + val, 0.f));
  int j = (int)(unsigned)(best & 0xffffffffu);
  out[r]               = dist;
  out[NB1 + 2 * r]     = (float)r;
  out[NB1 + 2 * r + 1] = (float)j;
}

extern "C" void kernel_launch(void* const* d_in, const int* in_sizes, int n_in,
                              void* d_out, int out_size, void* d_ws, size_t ws_size,
                              hipStream_t stream) {
  const float* d1 = (const float*)d_in[0];
  const float* d2 = (const float*)d_in[1];
  float* out = (float*)d_out;

  char* w = (char*)d_ws;
  float* asq = (float*)w;                                   // 32 KB
  float* bsq = (float*)(w + 32768);                         // 32 KB
  _Float16* A2 = (_Float16*)(w + 65536);                    // 4 MB
  _Float16* B2 = (_Float16*)(w + 65536 + 4194304);          // 4 MB
  unsigned long long* cand =
      (unsigned long long*)(w + 65536 + 2 * 4194304);       // 4 MB

  convert_kernel<<<(NB1 + NB2) / 8, 256, 0, stream>>>(d1, d2, A2, B2, asq, bsq);

  mfma_match_kernel<<<(NB1 / 128) * (NB2 / 128), 256, 0, stream>>>(
      A2, B2, bsq, cand);

  final_kernel<<<NB1 / 256, 256, 0, stream>>>(cand, asq, out);
}

// Round 5
// 123.542 us; speedup vs baseline: 2.7390x; 1.0635x over previous
//
#include <hip/hip_runtime.h>
#include <cstdint>

#define NB1 8192
#define NB2 8192
#define DDIM 128
#define KROW 256           // stored row: [hi(128) | lo(128)] f16
#define NKITER 12          // virtual K = 384 (hi*hi + lo*hi + hi*lo)

using half8   = __attribute__((ext_vector_type(8))) _Float16;
using half4   = __attribute__((ext_vector_type(4))) _Float16;
using float4v = __attribute__((ext_vector_type(4))) float;

typedef __attribute__((address_space(3))) void       lds_void;
typedef const __attribute__((address_space(1))) void glb_void;

__device__ inline unsigned long long packkey(float v, int j) {
  unsigned u = __float_as_uint(v);
  u = (u & 0x80000000u) ? ~u : (u | 0x80000000u);  // monotone float->uint
  return ((unsigned long long)u << 32) | (unsigned)j;
}

// virtual kt -> source 32-f16 chunk index within the [hi|lo] row
__device__ __forceinline__ int a_src(int kt) { return (kt < 8) ? kt : kt - 8; } // hi,lo,hi
__device__ __forceinline__ int b_src(int kt) { return (kt < 4) ? kt : kt - 4; } // hi,hi,lo

// ---------------------------------------------------------------------------
// Kernel 0: fp32 -> f16 hi/lo split (row = [hi|lo], 256 f16) + squared norms
// + init packed argmin keys. One wave per 2 rows; float4 loads, half4 stores.
// ---------------------------------------------------------------------------
__global__ __launch_bounds__(256) void convert_kernel(
    const float* __restrict__ d1, const float* __restrict__ d2,
    _Float16* __restrict__ A2, _Float16* __restrict__ B2,
    float* __restrict__ asq, float* __restrict__ bsq,
    unsigned long long* __restrict__ packed) {
  int gid  = blockIdx.x * 256 + threadIdx.x;
  int wv   = gid >> 6;
  int lane = gid & 63;
  int rowc = 2 * wv + (lane >> 5);
  bool isA = rowc < NB1;
  const float* src = isA ? d1 : d2;
  int row = isA ? rowc : rowc - NB1;
  int k4  = (lane & 31) * 4;

  float4 v = *(const float4*)&src[row * DDIM + k4];
  _Float16 h0 = (_Float16)v.x, h1 = (_Float16)v.y;
  _Float16 h2 = (_Float16)v.z, h3 = (_Float16)v.w;
  half4 hh = {h0, h1, h2, h3};
  half4 ll = {(_Float16)(v.x - (float)h0), (_Float16)(v.y - (float)h1),
              (_Float16)(v.z - (float)h2), (_Float16)(v.w - (float)h3)};

  _Float16* dst = (isA ? A2 : B2) + (size_t)row * KROW;
  *(half4*)&dst[k4]       = hh;
  *(half4*)&dst[128 + k4] = ll;

  float s = v.x * v.x + v.y * v.y + v.z * v.z + v.w * v.w;
  #pragma unroll
  for (int off = 16; off > 0; off >>= 1) s += __shfl_xor(s, off, 64);
  if ((lane & 31) == 0) (isA ? asq : bsq)[row] = s;

  if (gid < NB1) packed[gid] = 0xFFFFFFFFFFFFFFFFull;  // +inf key
}

// ---------------------------------------------------------------------------
// Kernel 1: MFMA GEMM (virtual K=384 f16, fp32 acc) + fused row argmin.
// 128x128 tile, 4 waves (2x2), 4x4 mfma_f32_16x16x32_f16 per wave.
// - XCD swizzle: per-XCD resident set = 8 A-tiles + 16 B-tiles (~2 MB < L2).
// - Double-buffered global_load_lds (16B) staging; one barrier per kt.
// - LDS cell (row r, chunk q) at 4r + ((q + (r>>1)) & 3): frag b128 reads are
//   conflict-free (verified: SQ_LDS_BANK_CONFLICT = 0); staging lanes fetch
//   the inverse-permuted global chunk.
// - Epilogue: register fold over c, pad-17 LDS lex-min -> 1 u64/row/block,
//   then device-scope atomicMin into packed[] (no cand array, no final pass).
// ---------------------------------------------------------------------------
__global__ __launch_bounds__(256, 3) void mfma_match_kernel(
    const _Float16* __restrict__ A2, const _Float16* __restrict__ B2,
    const float* __restrict__ bsq, unsigned long long* __restrict__ packed) {
  __shared__ unsigned long long smem[2 * 128 * 17];  // 34816 B, aliased
  _Float16* Asb = (_Float16*)smem;                   // 2 buffers x 4096 f16
  _Float16* Bsb = (_Float16*)smem + 8192;            // 2 buffers x 4096 f16

  const int t    = threadIdx.x;
  const int lane = t & 63;
  const int wid  = t >> 6;
  const int wm = wid >> 1, wn = wid & 1;
  const int lx = lane & 15, q = lane >> 4;

  // L2/XCD locality swizzle (dispatch round-robins id%8 across XCDs).
  const int id = blockIdx.x;
  const int xc = id & 7, kk = id >> 3;
  const int bx = ((kk >> 3) & 7) * 8 + xc;
  const int by = (kk & 7) + ((kk >> 6) & 7) * 8;
  const int row0 = bx * 128, col0 = by * 128;

  // Staging lane geometry. Slab = 16 rows x 4 cells(16B). Wave stages slabs
  // {2*wid, 2*wid+1}. Lane l -> row l>>2, LDS slot l&3; global chunk for that
  // slot is the inverse bank-swizzle: q = (slot - (row>>1)) & 3.
  const int sA   = wid * 2;
  const int rloc = lane >> 2;
  const int qch  = ((lane & 3) - (rloc >> 1)) & 3;
  const int rA0  = sA * 16 + rloc;
  const int kofs = qch * 8;

  float4v acc[4][4];
  #pragma unroll
  for (int r = 0; r < 4; ++r)
    #pragma unroll
    for (int c = 0; c < 4; ++c) acc[r][c] = (float4v){0.f, 0.f, 0.f, 0.f};

  // Prefetch bsq + column ids for the epilogue.
  float bq[4]; int jc[4];
  #pragma unroll
  for (int c = 0; c < 4; ++c) {
    jc[c] = col0 + wn * 64 + 16 * c + lx;
    bq[c] = bsq[jc[c]];
  }

  auto stage = [&](int kt, int buf) {
    const _Float16* ga =
        A2 + (size_t)(row0 + rA0) * KROW + a_src(kt) * 32 + kofs;
    __builtin_amdgcn_global_load_lds((glb_void*)ga,
        (lds_void*)(Asb + buf * 4096 + sA * 512), 16, 0, 0);
    __builtin_amdgcn_global_load_lds((glb_void*)(ga + 16 * KROW),
        (lds_void*)(Asb + buf * 4096 + (sA + 1) * 512), 16, 0, 0);
    const _Float16* gb =
        B2 + (size_t)(col0 + rA0) * KROW + b_src(kt) * 32 + kofs;
    __builtin_amdgcn_global_load_lds((glb_void*)gb,
        (lds_void*)(Bsb + buf * 4096 + sA * 512), 16, 0, 0);
    __builtin_amdgcn_global_load_lds((glb_void*)(gb + 16 * KROW),
        (lds_void*)(Bsb + buf * 4096 + (sA + 1) * 512), 16, 0, 0);
  };

  stage(0, 0);

  const int sw = ((q + (lx >> 1)) & 3) * 8;   // bank-swizzled chunk offset

  #pragma unroll
  for (int kt = 0; kt < NKITER; ++kt) {
    __syncthreads();  // stage(kt) drained (vmcnt0 before barrier); WAR safe
    if (kt < NKITER - 1) stage(kt + 1, (kt + 1) & 1);
    const _Float16* Ab = Asb + (kt & 1) * 4096;
    const _Float16* Bb = Bsb + (kt & 1) * 4096;
    half8 af[4], bf[4];
    #pragma unroll
    for (int r = 0; r < 4; ++r)
      af[r] = *(const half8*)&Ab[(wm * 64 + 16 * r + lx) * 32 + sw];
    #pragma unroll
    for (int c = 0; c < 4; ++c)
      bf[c] = *(const half8*)&Bb[(wn * 64 + 16 * c + lx) * 32 + sw];
    #pragma unroll
    for (int r = 0; r < 4; ++r)
      #pragma unroll
      for (int c = 0; c < 4; ++c)
        acc[r][c] = __builtin_amdgcn_mfma_f32_16x16x32_f16(
            af[r], bf[c], acc[r][c], 0, 0, 0);
  }

  // ---- Epilogue. C/D layout: col = lane&15, row = q*4 + reg. ----
  __syncthreads();  // all frag reads done before aliasing staging LDS
  #pragma unroll
  for (int r = 0; r < 4; ++r) {
    #pragma unroll
    for (int reg = 0; reg < 4; ++reg) {
      float bv = 1e30f; int bj = 0;
      #pragma unroll
      for (int c = 0; c < 4; ++c) {  // jc ascending -> strict < keeps min j
        float val = fmaf(-2.f, acc[r][c][reg], bq[c]);
        if (val < bv) { bv = val; bj = jc[c]; }
      }
      int mrow = wm * 64 + 16 * r + 4 * q + reg;
      smem[(wn * 128 + mrow) * 17 + lx] = packkey(bv, bj);
    }
  }
  __syncthreads();
  if (t < 128) {
    unsigned long long best = ~0ull;
    #pragma unroll
    for (int w = 0; w < 2; ++w)
      #pragma unroll
      for (int x = 0; x < 16; ++x) {
        unsigned long long k = smem[(w * 128 + t) * 17 + x];
        if (k < best) best = k;
      }
    atomicMin(&packed[row0 + t], best);  // device-scope; lex (val, idx) min
  }
}

// ---------------------------------------------------------------------------
// Kernel 2: decode packed keys, write outputs.
// ---------------------------------------------------------------------------
__global__ __launch_bounds__(256) void out_kernel(
    const unsigned long long* __restrict__ packed,
    const float* __restrict__ asq, float* __restrict__ out) {
  int r = blockIdx.x * 256 + threadIdx.x;
  unsigned long long best = packed[r];
  unsigned u = (unsigned)(best >> 32);
  u = (u & 0x80000000u) ? (u & 0x7fffffffu) : ~u;   // invert monotone map
  float val  = __uint_as_float(u);
  float dist = sqrtf(fmaxf(asq[r] + val, 0.f));
  int j = (int)(unsigned)(best & 0xffffffffu);
  out[r]               = dist;
  out[NB1 + 2 * r]     = (float)r;
  out[NB1 + 2 * r + 1] = (float)j;
}

extern "C" void kernel_launch(void* const* d_in, const int* in_sizes, int n_in,
                              void* d_out, int out_size, void* d_ws, size_t ws_size,
                              hipStream_t stream) {
  const float* d1 = (const float*)d_in[0];
  const float* d2 = (const float*)d_in[1];
  float* out = (float*)d_out;

  char* w = (char*)d_ws;
  float* asq = (float*)w;                                   // 32 KB
  float* bsq = (float*)(w + 32768);                         // 32 KB
  _Float16* A2 = (_Float16*)(w + 65536);                    // 4 MB
  _Float16* B2 = (_Float16*)(w + 65536 + 4194304);          // 4 MB
  unsigned long long* packed =
      (unsigned long long*)(w + 65536 + 2 * 4194304);       // 64 KB

  convert_kernel<<<(NB1 + NB2) / 8, 256, 0, stream>>>(
      d1, d2, A2, B2, asq, bsq, packed);

  mfma_match_kernel<<<(NB1 / 128) * (NB2 / 128), 256, 0, stream>>>(
      A2, B2, bsq, packed);

  out_kernel<<<NB1 / 256, 256, 0, stream>>>(packed, asq, out);
}